// Round 6
// baseline (11037.870 us; speedup 1.0000x reference)
//
#include <hip/hip_runtime.h>

// BasicMGU scan, hang-proof XCD-local dataflow.
// 8 batch-groups x 8 rows; group = blockIdx&7 (round-robin => one XCD/group,
// heuristic only); 16 WGs/group each owning 32 cols. Exchange h and g=h*f as
// (epoch16|bf16hi),(epoch16|bf16lo) dword pairs through TWO buffers:
//   L: plain stores -> producer's XCD L2; polled with sc0 loads (fast path)
//   F: sc0 sc1 stores/loads at the IF coherence point (R4-proven fallback)
// Consumers poll BOTH and per-lane take whichever tag matches first -- the
// F path guarantees progress, so no placement/coherence assumption can hang.
// Weights register-resident (AGPR-pinned), 3-term bf16 MFMA split.

typedef __bf16 bf16;
typedef __attribute__((ext_vector_type(8))) __bf16 bf16x8;
typedef __attribute__((ext_vector_type(4))) float f32x4;
typedef __attribute__((ext_vector_type(4))) unsigned u32x4;
typedef __attribute__((ext_vector_type(2))) unsigned u32x2;

#define MFMA16(a, b, c) __builtin_amdgcn_mfma_f32_16x16x32_bf16((a), (b), (c), 0, 0, 0)
#define WB(q) __builtin_bit_cast(bf16x8, q)

constexpr int Tc = 1024, Dc = 512, Uc = 512;
constexpr int GRPS = 8, GR = 8, SLICES = 16, NWG = GRPS * SLICES;  // 128 WGs

constexpr size_t BUF = (size_t)GRPS * GR * Uc * 2 * 4;  // 256 KiB per buffer
constexpr size_t WS_HL = 0, WS_GL = BUF, WS_HF = 2 * BUF, WS_GF = 3 * BUF;
constexpr size_t WS_ZERO = 4 * BUF;  // 1 MiB

// ---- 16-quad tagged loads (one lane's 32 values = 64 dwords) ----
__device__ inline void load16qL(const unsigned* p, u32x4 b[16]) {  // sc0: L2-served
  asm volatile(
      "global_load_dwordx4 %0,  %16, off sc0\n\t"
      "global_load_dwordx4 %1,  %16, off offset:16 sc0\n\t"
      "global_load_dwordx4 %2,  %16, off offset:32 sc0\n\t"
      "global_load_dwordx4 %3,  %16, off offset:48 sc0\n\t"
      "global_load_dwordx4 %4,  %16, off offset:256 sc0\n\t"
      "global_load_dwordx4 %5,  %16, off offset:272 sc0\n\t"
      "global_load_dwordx4 %6,  %16, off offset:288 sc0\n\t"
      "global_load_dwordx4 %7,  %16, off offset:304 sc0\n\t"
      "global_load_dwordx4 %8,  %16, off offset:512 sc0\n\t"
      "global_load_dwordx4 %9,  %16, off offset:528 sc0\n\t"
      "global_load_dwordx4 %10, %16, off offset:544 sc0\n\t"
      "global_load_dwordx4 %11, %16, off offset:560 sc0\n\t"
      "global_load_dwordx4 %12, %16, off offset:768 sc0\n\t"
      "global_load_dwordx4 %13, %16, off offset:784 sc0\n\t"
      "global_load_dwordx4 %14, %16, off offset:800 sc0\n\t"
      "global_load_dwordx4 %15, %16, off offset:816 sc0"
      : "=&v"(b[0]), "=&v"(b[1]), "=&v"(b[2]), "=&v"(b[3]),
        "=&v"(b[4]), "=&v"(b[5]), "=&v"(b[6]), "=&v"(b[7]),
        "=&v"(b[8]), "=&v"(b[9]), "=&v"(b[10]), "=&v"(b[11]),
        "=&v"(b[12]), "=&v"(b[13]), "=&v"(b[14]), "=&v"(b[15])
      : "v"(p) : "memory");
}

__device__ inline void load16qF(const unsigned* p, u32x4 b[16]) {  // sc0 sc1: IF-served
  asm volatile(
      "global_load_dwordx4 %0,  %16, off sc0 sc1\n\t"
      "global_load_dwordx4 %1,  %16, off offset:16 sc0 sc1\n\t"
      "global_load_dwordx4 %2,  %16, off offset:32 sc0 sc1\n\t"
      "global_load_dwordx4 %3,  %16, off offset:48 sc0 sc1\n\t"
      "global_load_dwordx4 %4,  %16, off offset:256 sc0 sc1\n\t"
      "global_load_dwordx4 %5,  %16, off offset:272 sc0 sc1\n\t"
      "global_load_dwordx4 %6,  %16, off offset:288 sc0 sc1\n\t"
      "global_load_dwordx4 %7,  %16, off offset:304 sc0 sc1\n\t"
      "global_load_dwordx4 %8,  %16, off offset:512 sc0 sc1\n\t"
      "global_load_dwordx4 %9,  %16, off offset:528 sc0 sc1\n\t"
      "global_load_dwordx4 %10, %16, off offset:544 sc0 sc1\n\t"
      "global_load_dwordx4 %11, %16, off offset:560 sc0 sc1\n\t"
      "global_load_dwordx4 %12, %16, off offset:768 sc0 sc1\n\t"
      "global_load_dwordx4 %13, %16, off offset:784 sc0 sc1\n\t"
      "global_load_dwordx4 %14, %16, off offset:800 sc0 sc1\n\t"
      "global_load_dwordx4 %15, %16, off offset:816 sc0 sc1"
      : "=&v"(b[0]), "=&v"(b[1]), "=&v"(b[2]), "=&v"(b[3]),
        "=&v"(b[4]), "=&v"(b[5]), "=&v"(b[6]), "=&v"(b[7]),
        "=&v"(b[8]), "=&v"(b[9]), "=&v"(b[10]), "=&v"(b[11]),
        "=&v"(b[12]), "=&v"(b[13]), "=&v"(b[14]), "=&v"(b[15])
      : "v"(p) : "memory");
}

__device__ inline bool freshq(const u32x4* b, unsigned tag) {
  unsigned acc = 0;
#pragma unroll
  for (int i = 0; i < 16; ++i) {
    u32x4 v = b[i];
    acc |= (v[0] ^ tag) | (v[1] ^ tag) | (v[2] ^ tag) | (v[3] ^ tag);
  }
  return (acc & 0xFFFF0000u) == 0;
}

// dual-path poll: break when every lane has a fresh snapshot from L or F
__device__ inline void pollq2(const unsigned* Lp, const unsigned* Fp,
                              unsigned tag, u32x4 b[16]) {
  u32x4 bL[16], bF[16];
  for (;;) {
    load16qL(Lp, bL);
    load16qF(Fp, bF);
    asm volatile("s_waitcnt vmcnt(0)" ::: "memory");
    __builtin_amdgcn_sched_barrier(0);  // rule 18: nothing hoists above the wait
    const bool okL = freshq(bL, tag);
    const bool okF = freshq(bF, tag);
    if (__ballot(!(okL || okF)) == 0) {
#pragma unroll
      for (int i = 0; i < 16; ++i) b[i] = okL ? bL[i] : bF[i];
      return;
    }
  }
}

// quad jj of one kb holds [hi(2jj), lo(2jj), hi(2jj+1), lo(2jj+1)]
__device__ inline void mk8(const u32x4* q, bf16x8& fh, bf16x8& fl) {
  union { unsigned d[4]; bf16x8 v; } H, L;
#pragma unroll
  for (int jj = 0; jj < 4; ++jj) {
    H.d[jj] = (q[jj][0] & 0xFFFFu) | (q[jj][2] << 16);
    L.d[jj] = (q[jj][1] & 0xFFFFu) | (q[jj][3] << 16);
  }
  fh = H.v;
  fl = L.v;
}

__device__ inline void store_pair2(unsigned* Lp, unsigned* Fp, unsigned tag, float v) {
  bf16 hi = (bf16)v;
  bf16 lo = (bf16)(v - (float)hi);
  u32x2 d;
  d[0] = tag | (unsigned)__builtin_bit_cast(unsigned short, hi);
  d[1] = tag | (unsigned)__builtin_bit_cast(unsigned short, lo);
  asm volatile("global_store_dwordx2 %0, %2, off\n\t"
               "global_store_dwordx2 %1, %2, off sc0 sc1"
               :: "v"(Lp), "v"(Fp), "v"(d) : "memory");
}

__global__ __launch_bounds__(256, 1)
void mgu_kernel(const float* __restrict__ x,
                const float* __restrict__ Wk, const float* __restrict__ Wr,
                const float* __restrict__ br,
                const float* __restrict__ Wu, const float* __restrict__ Wur,
                const float* __restrict__ bur,
                unsigned* __restrict__ ws0, float* __restrict__ out) {
  __shared__ float red[2][4][2][16][16];  // [phase][wave][ct][row][col16]

  unsigned* HL = ws0 + WS_HL / 4;
  unsigned* GL = ws0 + WS_GL / 4;
  unsigned* HF = ws0 + WS_HF / 4;
  unsigned* GF = ws0 + WS_GF / 4;

  const int wg = blockIdx.x;
  const int g = wg & 7;          // batch group -> XCD (round-robin heuristic)
  const int cw = wg >> 3;        // column slice 0..15
  const int c0 = cw * 32;
  const int tid = threadIdx.x;
  const int w = tid >> 6, lane = tid & 63;
  const int dcol = lane & 15, kq = lane >> 4;
  const int rrow = dcol & 7;     // real batch row (rows 8..15 duplicate 0..7)
  const int kbase = w * 128 + kq * 8;

  // ---- weights into AGPR-pinned registers. Wr/Wur hi+lo; Wk/Wu hi only.
  f32x4 WKH[2][4], WRH[2][4], WRL[2][4], WUH[2][4], WQH[2][4], WQL[2][4];
#pragma unroll
  for (int ct = 0; ct < 2; ++ct) {
    const int col = c0 + ct * 16 + dcol;
#pragma unroll
    for (int kb = 0; kb < 4; ++kb) {
      union { bf16x8 v; f32x4 f; } a_, b_, c_, d_, e_, q_;
#pragma unroll
      for (int j = 0; j < 8; ++j) {
        const size_t ko = (size_t)(kbase + kb * 32 + j) * Uc + col;
        { float v = Wk[ko]; a_.v[j] = (bf16)v; }
        { float v = Wr[ko]; bf16 h0 = (bf16)v; b_.v[j] = h0; c_.v[j] = (bf16)(v - (float)h0); }
        { float v = Wu[ko]; d_.v[j] = (bf16)v; }
        { float v = Wur[ko]; bf16 h0 = (bf16)v; e_.v[j] = h0; q_.v[j] = (bf16)(v - (float)h0); }
      }
      WKH[ct][kb] = a_.f; WRH[ct][kb] = b_.f; WRL[ct][kb] = c_.f;
      WUH[ct][kb] = d_.f; WQH[ct][kb] = e_.f; WQL[ct][kb] = q_.f;
    }
  }
#pragma unroll
  for (int ct = 0; ct < 2; ++ct)
#pragma unroll
    for (int kb = 0; kb < 4; ++kb)
      asm volatile("" : "+a"(WKH[ct][kb]), "+a"(WRH[ct][kb]), "+a"(WRL[ct][kb]),
                       "+a"(WUH[ct][kb]), "+a"(WQH[ct][kb]), "+a"(WQL[ct][kb]));

  // ---- finalizer: wave w owns rows {2w, 2w+1}; 1 output/lane
  const int sub = lane >> 5, colL = lane & 31;
  const int fct = colL >> 4, fc16 = colL & 15;
  const int frow = 2 * w + sub;
  const float brv = br[c0 + colL], burv = bur[c0 + colL];

  const size_t ldoff = ((size_t)(g * GR + rrow) * Uc + kbase) * 2;
  const unsigned* HldL = HL + ldoff;
  const unsigned* HldF = HF + ldoff;
  const unsigned* GldL = GL + ldoff;
  const unsigned* GldF = GF + ldoff;
  const size_t stoff = ((size_t)(g * GR + frow) * Uc + c0 + colL) * 2;
  unsigned* GsL = GL + stoff;  unsigned* GsF = GF + stoff;
  unsigned* HsL = HL + stoff;  unsigned* HsF = HF + stoff;

  const float* xptr = x + (size_t)(g * GR + rrow) * Tc * Dc + kbase;

  float h_keep = 0.f, f_keep = 0.f;
  f32x4 axk[2], axu[2];
  f32x4 xr[8];

  auto do_x_load = [&](int t) {  // raw f32 loads only (in flight during phase 2)
    const float* xp = xptr + (size_t)t * Dc;
#pragma unroll
    for (int kb = 0; kb < 4; ++kb) {
      xr[2 * kb] = *(const f32x4*)(xp + kb * 32);
      xr[2 * kb + 1] = *(const f32x4*)(xp + kb * 32 + 4);
    }
  };
  auto do_x_mfma = [&]() {  // convert + x@Wk, x@Wu partials
    bf16x8 xh[4], xl[4];
#pragma unroll
    for (int kb = 0; kb < 4; ++kb) {
      f32x4 a = xr[2 * kb], b = xr[2 * kb + 1];
#pragma unroll
      for (int j = 0; j < 4; ++j) {
        bf16 h0 = (bf16)a[j]; xh[kb][j] = h0; xl[kb][j] = (bf16)(a[j] - (float)h0);
        bf16 h1 = (bf16)b[j]; xh[kb][4 + j] = h1; xl[kb][4 + j] = (bf16)(b[j] - (float)h1);
      }
    }
#pragma unroll
    for (int ct = 0; ct < 2; ++ct) {
      f32x4 k0 = {0.f, 0.f, 0.f, 0.f}, k1 = k0, u0 = k0, u1 = k0;
#pragma unroll
      for (int kb = 0; kb < 4; ++kb) {
        k0 = MFMA16(xh[kb], WB(WKH[ct][kb]), k0);
        k1 = MFMA16(xl[kb], WB(WKH[ct][kb]), k1);
        u0 = MFMA16(xh[kb], WB(WUH[ct][kb]), u0);
        u1 = MFMA16(xl[kb], WB(WUH[ct][kb]), u1);
      }
      axk[ct] = k0 + k1;
      axu[ct] = u0 + u1;
    }
  };

  do_x_load(0);
  do_x_mfma();

  for (int t = 0; t < Tc; ++t) {
    const unsigned tag0 = (unsigned)t << 16, tag1 = (unsigned)(t + 1) << 16;
    u32x4 b[16];

    // ---- phase 1: a_f = x@Wk (done) + h@Wr
    pollq2(HldL, HldF, tag0, b);
    {
      bf16x8 fh[4], fl[4];
#pragma unroll
      for (int kb = 0; kb < 4; ++kb) mk8(&b[kb * 4], fh[kb], fl[kb]);
#pragma unroll
      for (int ct = 0; ct < 2; ++ct) {
        f32x4 r0 = {0.f, 0.f, 0.f, 0.f}, r1 = r0, r2 = r0;
#pragma unroll
        for (int kb = 0; kb < 4; ++kb) {
          r0 = MFMA16(fh[kb], WB(WRH[ct][kb]), r0);
          r1 = MFMA16(fl[kb], WB(WRH[ct][kb]), r1);
          r2 = MFMA16(fh[kb], WB(WRL[ct][kb]), r2);
        }
        f32x4 r = axk[ct] + r0 + r1 + r2;
#pragma unroll
        for (int i = 0; i < 4; ++i) red[0][w][ct][kq * 4 + i][dcol] = r[i];
      }
    }
    __syncthreads();
    {
      float af = red[0][0][fct][frow][fc16] + red[0][1][fct][frow][fc16] +
                 red[0][2][fct][frow][fc16] + red[0][3][fct][frow][fc16] + brv;
      float f = __builtin_amdgcn_rcpf(1.f + __expf(-af));
      f_keep = f;
      store_pair2(GsL, GsF, tag1, h_keep * f);  // g = h.*f, exact f32 product
    }
    if (t + 1 < Tc) do_x_load(t + 1);  // x(t+1) in flight under the G wait

    // ---- phase 2: a_h = x@Wu (done) + g@Wur
    pollq2(GldL, GldF, tag1, b);
    {
      bf16x8 gh[4], gl[4];
#pragma unroll
      for (int kb = 0; kb < 4; ++kb) mk8(&b[kb * 4], gh[kb], gl[kb]);
#pragma unroll
      for (int ct = 0; ct < 2; ++ct) {
        f32x4 q0 = {0.f, 0.f, 0.f, 0.f}, q1 = q0, q2 = q0;
#pragma unroll
        for (int kb = 0; kb < 4; ++kb) {
          q0 = MFMA16(gh[kb], WB(WQH[ct][kb]), q0);
          q1 = MFMA16(gl[kb], WB(WQH[ct][kb]), q1);
          q2 = MFMA16(gh[kb], WB(WQL[ct][kb]), q2);
        }
        f32x4 qv = axu[ct] + q0 + q1 + q2;
#pragma unroll
        for (int i = 0; i < 4; ++i) red[1][w][ct][kq * 4 + i][dcol] = qv[i];
      }
    }
    __syncthreads();
    {
      float ah = red[1][0][fct][frow][fc16] + red[1][1][fct][frow][fc16] +
                 red[1][2][fct][frow][fc16] + red[1][3][fct][frow][fc16] + burv;
      float e2 = __expf(2.f * ah);
      float hc = 1.f - 2.f * __builtin_amdgcn_rcpf(e2 + 1.f);  // tanh
      float hn = h_keep + f_keep * (hc - h_keep);
      h_keep = hn;
      store_pair2(HsL, HsF, tag1, hn);
      if (t == Tc - 1) out[(size_t)(g * GR + frow) * Uc + c0 + colL] = hn;
    }
    if (t + 1 < Tc) do_x_mfma();  // convert + x-MFMAs for t+1
  }
}

extern "C" void kernel_launch(void* const* d_in, const int* in_sizes, int n_in,
                              void* d_out, int out_size, void* d_ws, size_t ws_size,
                              hipStream_t stream) {
  const float* x   = (const float*)d_in[0];
  const float* Wk  = (const float*)d_in[1];
  const float* Wr  = (const float*)d_in[2];
  const float* br  = (const float*)d_in[3];
  const float* Wu  = (const float*)d_in[4];
  const float* Wur = (const float*)d_in[5];
  const float* bur = (const float*)d_in[6];
  float* out = (float*)d_out;

  hipMemsetAsync(d_ws, 0, WS_ZERO, stream);  // h0 = 0 (epoch 0), both paths

  hipLaunchKernelGGL(mgu_kernel, dim3(NWG), dim3(256), 0, stream,
                     x, Wk, Wr, br, Wu, Wur, bur, (unsigned*)d_ws, out);
}

// Round 7
// 8914.803 us; speedup vs baseline: 1.2382x; 1.2382x over previous
//
#include <hip/hip_runtime.h>

// BasicMGU scan, narrow-sentinel dataflow.
// 8 batch-groups x 8 rows; 16 WGs/group each owning 32 cols; 4 waves/WG each
// owning a K-quarter. Exchange h and g=h*f as UNTAGGED packed dwords
// (bf16hi | bf16lo<<16) at IF scope (sc0 sc1). Release ordering: data stores
// -> vmcnt(0) -> per-wave sentinel (step tag). Consumer wave polls only its 16
// source sentinels (1 dword/lane), then loads data ONCE. Intra-WG syncthreads
// makes every WG wait on every WG each phase => producer can't overwrite slot t
// until all consumers read it (WAR closed). Weights AGPR-pinned, 3-term split.

typedef __bf16 bf16;
typedef __attribute__((ext_vector_type(8))) __bf16 bf16x8;
typedef __attribute__((ext_vector_type(4))) float f32x4;
typedef __attribute__((ext_vector_type(4))) unsigned u32x4;

#define MFMA16(a, b, c) __builtin_amdgcn_mfma_f32_16x16x32_bf16((a), (b), (c), 0, 0, 0)
#define WB(q) __builtin_bit_cast(bf16x8, q)

constexpr int Tc = 1024, Dc = 512, Uc = 512;
constexpr int GRPS = 8, GR = 8, NWG = GRPS * 16;  // 128 WGs

// ws: sentH[8][64] @0 (2KB), sentG[8][64] @2048, H[8][8][512] dwords @4096,
//     G same @4096+128K. All zeroed per launch (h0 = 0, sentinels = 0).
constexpr size_t WS_SH = 0, WS_SG = 2048, WS_H = 4096;
constexpr size_t WS_G = WS_H + (size_t)GRPS * GR * Uc * 4;
constexpr size_t WS_ZERO = WS_G + (size_t)GRPS * GR * Uc * 4;  // 266240

// one lane's 32 packed values: 8 dwordx4, IF-coherent
__device__ inline void load8q(const unsigned* p, u32x4 b[8]) {
  asm volatile(
      "global_load_dwordx4 %0, %8, off sc0 sc1\n\t"
      "global_load_dwordx4 %1, %8, off offset:16 sc0 sc1\n\t"
      "global_load_dwordx4 %2, %8, off offset:128 sc0 sc1\n\t"
      "global_load_dwordx4 %3, %8, off offset:144 sc0 sc1\n\t"
      "global_load_dwordx4 %4, %8, off offset:256 sc0 sc1\n\t"
      "global_load_dwordx4 %5, %8, off offset:272 sc0 sc1\n\t"
      "global_load_dwordx4 %6, %8, off offset:384 sc0 sc1\n\t"
      "global_load_dwordx4 %7, %8, off offset:400 sc0 sc1"
      : "=&v"(b[0]), "=&v"(b[1]), "=&v"(b[2]), "=&v"(b[3]),
        "=&v"(b[4]), "=&v"(b[5]), "=&v"(b[6]), "=&v"(b[7])
      : "v"(p) : "memory");
}

// poll 1 sentinel dword per lane until all 64 lanes see the exact step tag
__device__ inline void poll_sent(const unsigned* sp, unsigned tag) {
  for (;;) {
    unsigned v;
    asm volatile("global_load_dword %0, %1, off sc0 sc1"
                 : "=v"(v) : "v"(sp) : "memory");
    asm volatile("s_waitcnt vmcnt(0)" ::: "memory");
    __builtin_amdgcn_sched_barrier(0);  // rule 18
    if (__ballot(v != tag) == 0) break;
  }
}

// 8 packed dwords (hi|lo<<16 per k) -> hi/lo bf16x8 fragments
__device__ inline void mk8(const u32x4* q, bf16x8& fh, bf16x8& fl) {
  union { unsigned d[4]; bf16x8 v; } H, L;
  const unsigned* u = (const unsigned*)q;
#pragma unroll
  for (int j = 0; j < 4; ++j) {
    H.d[j] = (u[2 * j] & 0xFFFFu) | (u[2 * j + 1] << 16);
    L.d[j] = (u[2 * j] >> 16) | (u[2 * j + 1] & 0xFFFF0000u);
  }
  fh = H.v;
  fl = L.v;
}

__device__ inline void store_val(unsigned* p, float v) {
  bf16 hi = (bf16)v;
  bf16 lo = (bf16)(v - (float)hi);
  unsigned d = (unsigned)__builtin_bit_cast(unsigned short, hi) |
               ((unsigned)__builtin_bit_cast(unsigned short, lo) << 16);
  asm volatile("global_store_dword %0, %1, off sc0 sc1" ::"v"(p), "v"(d) : "memory");
}

__global__ __launch_bounds__(256, 1)
void mgu_kernel(const float* __restrict__ x,
                const float* __restrict__ Wk, const float* __restrict__ Wr,
                const float* __restrict__ br,
                const float* __restrict__ Wu, const float* __restrict__ Wur,
                const float* __restrict__ bur,
                unsigned* __restrict__ ws0, float* __restrict__ out) {
  __shared__ float red[2][4][2][16][16];  // [phase][wave][ct][row][col16]

  unsigned* sentH = ws0 + WS_SH / 4;
  unsigned* sentG = ws0 + WS_SG / 4;
  unsigned* Hd = ws0 + WS_H / 4;
  unsigned* Gd = ws0 + WS_G / 4;

  const int wg = blockIdx.x;
  const int g = wg & 7, cw = wg >> 3;
  const int c0 = cw * 32;
  const int tid = threadIdx.x;
  const int w = tid >> 6, lane = tid & 63;
  const int dcol = lane & 15, kq = lane >> 4;
  const int rrow = dcol & 7;              // real batch row (dup for MFMA M=16)
  const int kbase = w * 128 + kq * 8;     // wave = K-quarter, lane picks sub-k

  // ---- weights into AGPR-pinned registers. Wr/Wur hi+lo; Wk/Wu hi only.
  f32x4 WKH[2][4], WRH[2][4], WRL[2][4], WUH[2][4], WQH[2][4], WQL[2][4];
#pragma unroll
  for (int ct = 0; ct < 2; ++ct) {
    const int col = c0 + ct * 16 + dcol;
#pragma unroll
    for (int kb = 0; kb < 4; ++kb) {
      union { bf16x8 v; f32x4 f; } a_, b_, c_, d_, e_, q_;
#pragma unroll
      for (int j = 0; j < 8; ++j) {
        const size_t ko = (size_t)(kbase + kb * 32 + j) * Uc + col;
        { float v = Wk[ko]; a_.v[j] = (bf16)v; }
        { float v = Wr[ko]; bf16 h0 = (bf16)v; b_.v[j] = h0; c_.v[j] = (bf16)(v - (float)h0); }
        { float v = Wu[ko]; d_.v[j] = (bf16)v; }
        { float v = Wur[ko]; bf16 h0 = (bf16)v; e_.v[j] = h0; q_.v[j] = (bf16)(v - (float)h0); }
      }
      WKH[ct][kb] = a_.f; WRH[ct][kb] = b_.f; WRL[ct][kb] = c_.f;
      WUH[ct][kb] = d_.f; WQH[ct][kb] = e_.f; WQL[ct][kb] = q_.f;
    }
  }
#pragma unroll
  for (int ct = 0; ct < 2; ++ct)
#pragma unroll
    for (int kb = 0; kb < 4; ++kb)
      asm volatile("" : "+a"(WKH[ct][kb]), "+a"(WRH[ct][kb]), "+a"(WRL[ct][kb]),
                       "+a"(WUH[ct][kb]), "+a"(WQH[ct][kb]), "+a"(WQL[ct][kb]));

  // ---- finalizer: wave w owns rows {2w, 2w+1}; 1 output value per lane
  const int sub = lane >> 5, colL = lane & 31;
  const int fct = colL >> 4, fc16 = colL & 15;
  const int frow = 2 * w + sub;
  const float brv = br[c0 + colL], burv = bur[c0 + colL];

  const size_t ldoff = (size_t)(g * GR + rrow) * Uc + kbase;
  const unsigned* Hld = Hd + ldoff;
  const unsigned* Gld = Gd + ldoff;
  const size_t stoff = (size_t)(g * GR + frow) * Uc + c0 + colL;
  unsigned* Hs = Hd + stoff;
  unsigned* Gs = Gd + stoff;
  // consumer wave w's k-range [128w,128w+128) is produced by WGs 4w..4w+3:
  // their sentinel slots are exactly [16w, 16w+16)
  const unsigned* sHp = sentH + g * 64 + 16 * w + (lane & 15);
  const unsigned* sGp = sentG + g * 64 + 16 * w + (lane & 15);
  unsigned* sHs = sentH + g * 64 + cw * 4 + w;
  unsigned* sGs = sentG + g * 64 + cw * 4 + w;

  const float* xptr = x + (size_t)(g * GR + rrow) * Tc * Dc + kbase;

  float h_keep = 0.f, f_keep = 0.f;
  f32x4 axk[2], axu[2];
  f32x4 xr[8];

  auto do_x_load = [&](int t) {
    const float* xp = xptr + (size_t)t * Dc;
#pragma unroll
    for (int kb = 0; kb < 4; ++kb) {
      xr[2 * kb] = *(const f32x4*)(xp + kb * 32);
      xr[2 * kb + 1] = *(const f32x4*)(xp + kb * 32 + 4);
    }
  };
  auto do_x_mfma = [&]() {
    bf16x8 xh[4], xl[4];
#pragma unroll
    for (int kb = 0; kb < 4; ++kb) {
      f32x4 a = xr[2 * kb], b = xr[2 * kb + 1];
#pragma unroll
      for (int j = 0; j < 4; ++j) {
        bf16 h0 = (bf16)a[j]; xh[kb][j] = h0; xl[kb][j] = (bf16)(a[j] - (float)h0);
        bf16 h1 = (bf16)b[j]; xh[kb][4 + j] = h1; xl[kb][4 + j] = (bf16)(b[j] - (float)h1);
      }
    }
#pragma unroll
    for (int ct = 0; ct < 2; ++ct) {
      f32x4 k0 = {0.f, 0.f, 0.f, 0.f}, k1 = k0, u0 = k0, u1 = k0;
#pragma unroll
      for (int kb = 0; kb < 4; ++kb) {
        k0 = MFMA16(xh[kb], WB(WKH[ct][kb]), k0);
        k1 = MFMA16(xl[kb], WB(WKH[ct][kb]), k1);
        u0 = MFMA16(xh[kb], WB(WUH[ct][kb]), u0);
        u1 = MFMA16(xl[kb], WB(WUH[ct][kb]), u1);
      }
      axk[ct] = k0 + k1;
      axu[ct] = u0 + u1;
    }
  };

  do_x_load(0);
  do_x_mfma();

  for (int t = 0; t < Tc; ++t) {
    u32x4 b[8];

    // ---- phase 1: a_f = x@Wk (done) + h@Wr
    poll_sent(sHp, (unsigned)t);            // h(t) published
    load8q(Hld, b);                         // data load, exactly once
    if (t + 1 < Tc) {
      const float* xp = xptr + (size_t)(t + 1) * Dc;
#pragma unroll
      for (int kb = 0; kb < 4; ++kb) {      // x(t+1) prefetch behind the data
        xr[2 * kb] = *(const f32x4*)(xp + kb * 32);
        xr[2 * kb + 1] = *(const f32x4*)(xp + kb * 32 + 4);
      }
      asm volatile("s_waitcnt vmcnt(8)" ::: "memory");  // h data done, x flying
    } else {
      asm volatile("s_waitcnt vmcnt(0)" ::: "memory");
    }
    __builtin_amdgcn_sched_barrier(0);
    {
      bf16x8 fh[4], fl[4];
#pragma unroll
      for (int kb = 0; kb < 4; ++kb) mk8(&b[kb * 2], fh[kb], fl[kb]);
#pragma unroll
      for (int ct = 0; ct < 2; ++ct) {
        f32x4 r0 = {0.f, 0.f, 0.f, 0.f}, r1 = r0, r2 = r0;
#pragma unroll
        for (int kb = 0; kb < 4; ++kb) {
          r0 = MFMA16(fh[kb], WB(WRH[ct][kb]), r0);
          r1 = MFMA16(fl[kb], WB(WRH[ct][kb]), r1);
          r2 = MFMA16(fh[kb], WB(WRL[ct][kb]), r2);
        }
        f32x4 r = axk[ct] + r0 + r1 + r2;
#pragma unroll
        for (int i = 0; i < 4; ++i) red[0][w][ct][kq * 4 + i][dcol] = r[i];
      }
    }
    __syncthreads();
    {
      float af = red[0][0][fct][frow][fc16] + red[0][1][fct][frow][fc16] +
                 red[0][2][fct][frow][fc16] + red[0][3][fct][frow][fc16] + brv;
      float f = __builtin_amdgcn_rcpf(1.f + __expf(-af));
      f_keep = f;
      store_val(Gs, h_keep * f);            // g = h.*f, exact f32 product
      asm volatile("s_waitcnt vmcnt(0)" ::: "memory");  // g committed at IF
      if (lane == 0)
        asm volatile("global_store_dword %0, %1, off sc0 sc1"
                     ::"v"(sGs), "v"((unsigned)(t + 1)) : "memory");
    }

    // ---- phase 2: a_h = x@Wu (done) + g@Wur
    poll_sent(sGp, (unsigned)(t + 1));      // g published
    load8q(Gld, b);
    asm volatile("s_waitcnt vmcnt(0)" ::: "memory");
    __builtin_amdgcn_sched_barrier(0);
    {
      bf16x8 gh[4], gl[4];
#pragma unroll
      for (int kb = 0; kb < 4; ++kb) mk8(&b[kb * 2], gh[kb], gl[kb]);
#pragma unroll
      for (int ct = 0; ct < 2; ++ct) {
        f32x4 q0 = {0.f, 0.f, 0.f, 0.f}, q1 = q0, q2 = q0;
#pragma unroll
        for (int kb = 0; kb < 4; ++kb) {
          q0 = MFMA16(gh[kb], WB(WQH[ct][kb]), q0);
          q1 = MFMA16(gl[kb], WB(WQH[ct][kb]), q1);
          q2 = MFMA16(gh[kb], WB(WQL[ct][kb]), q2);
        }
        f32x4 qv = axu[ct] + q0 + q1 + q2;
#pragma unroll
        for (int i = 0; i < 4; ++i) red[1][w][ct][kq * 4 + i][dcol] = qv[i];
      }
    }
    __syncthreads();
    {
      float ah = red[1][0][fct][frow][fc16] + red[1][1][fct][frow][fc16] +
                 red[1][2][fct][frow][fc16] + red[1][3][fct][frow][fc16] + burv;
      float e2 = __expf(2.f * ah);
      float hc = 1.f - 2.f * __builtin_amdgcn_rcpf(e2 + 1.f);  // tanh
      float hn = h_keep + f_keep * (hc - h_keep);
      h_keep = hn;
      store_val(Hs, hn);
      if (t == Tc - 1) out[(size_t)(g * GR + frow) * Uc + c0 + colL] = hn;
      asm volatile("s_waitcnt vmcnt(0)" ::: "memory");  // h committed at IF
      if (lane == 0)
        asm volatile("global_store_dword %0, %1, off sc0 sc1"
                     ::"v"(sHs), "v"((unsigned)(t + 1)) : "memory");
    }
    if (t + 1 < Tc) do_x_mfma();  // x(t+1) convert + x-MFMAs off the wait path
  }
}

extern "C" void kernel_launch(void* const* d_in, const int* in_sizes, int n_in,
                              void* d_out, int out_size, void* d_ws, size_t ws_size,
                              hipStream_t stream) {
  const float* x   = (const float*)d_in[0];
  const float* Wk  = (const float*)d_in[1];
  const float* Wr  = (const float*)d_in[2];
  const float* br  = (const float*)d_in[3];
  const float* Wu  = (const float*)d_in[4];
  const float* Wur = (const float*)d_in[5];
  const float* bur = (const float*)d_in[6];
  float* out = (float*)d_out;

  hipMemsetAsync(d_ws, 0, WS_ZERO, stream);  // h0 = 0, sentinels = 0

  hipLaunchKernelGGL(mgu_kernel, dim3(NWG), dim3(256), 0, stream,
                     x, Wk, Wr, br, Wu, Wur, bur, (unsigned*)d_ws, out);
}

// Round 8
// 8296.902 us; speedup vs baseline: 1.3304x; 1.0745x over previous
//
#include <hip/hip_runtime.h>

// BasicMGU scan, minimum-leg dataflow.
// 8 batch-groups x 8 rows; group g = blockIdx&7 (round-robin -> XCD-local,
// heuristic only); 16 WGs/group each owning 32 cols; 4 waves/WG each owning a
// K-quarter. Exchange h and g=h*f as (tag16|bf16hi),(tag16|bf16lo) dword pairs
// at IF scope (sc0 sc1). Producer stores are FIRE-AND-FORGET (no vmcnt, no
// sentinel); consumers poll the DATA until all embedded tags match: detection
// IS the data load. Slots are PARITY DOUBLE-BUFFERED (slot = step&1):
// overwriting a version requires being 2 full steps ahead, which the depth-2
// syncthreads dependency fan provably forbids -> no hang, no stale read.
// Wave 0 of each WG finalizes all 8 rows (consumers wait on 4 producer waves,
// not 16). Weights AGPR-pinned; 3-term bf16 MFMA split on recurrent mats.

typedef __bf16 bf16;
typedef __attribute__((ext_vector_type(8))) __bf16 bf16x8;
typedef __attribute__((ext_vector_type(4))) float f32x4;
typedef __attribute__((ext_vector_type(4))) unsigned u32x4;
typedef __attribute__((ext_vector_type(2))) unsigned u32x2;

#define MFMA16(a, b, c) __builtin_amdgcn_mfma_f32_16x16x32_bf16((a), (b), (c), 0, 0, 0)
#define WB(q) __builtin_bit_cast(bf16x8, q)

constexpr int Tc = 1024, Dc = 512, Uc = 512;
constexpr int GRPS = 8, GR = 8, NWG = GRPS * 16;  // 128 WGs

// dwords per parity buffer: 8 grp x 8 rows x 512 k x 2 dwords
constexpr size_t HPAR = (size_t)GRPS * GR * Uc * 2;        // 65536 dwords
constexpr size_t WS_ZERO = 4 * HPAR * 4;                   // H[2] + G[2] = 1 MiB

// one lane's 32 values (64 tagged dwords) as 16 dwordx4, IF-coherent
__device__ inline void load16q(const unsigned* p, u32x4 b[16]) {
  asm volatile(
      "global_load_dwordx4 %0,  %16, off sc0 sc1\n\t"
      "global_load_dwordx4 %1,  %16, off offset:16 sc0 sc1\n\t"
      "global_load_dwordx4 %2,  %16, off offset:32 sc0 sc1\n\t"
      "global_load_dwordx4 %3,  %16, off offset:48 sc0 sc1\n\t"
      "global_load_dwordx4 %4,  %16, off offset:256 sc0 sc1\n\t"
      "global_load_dwordx4 %5,  %16, off offset:272 sc0 sc1\n\t"
      "global_load_dwordx4 %6,  %16, off offset:288 sc0 sc1\n\t"
      "global_load_dwordx4 %7,  %16, off offset:304 sc0 sc1\n\t"
      "global_load_dwordx4 %8,  %16, off offset:512 sc0 sc1\n\t"
      "global_load_dwordx4 %9,  %16, off offset:528 sc0 sc1\n\t"
      "global_load_dwordx4 %10, %16, off offset:544 sc0 sc1\n\t"
      "global_load_dwordx4 %11, %16, off offset:560 sc0 sc1\n\t"
      "global_load_dwordx4 %12, %16, off offset:768 sc0 sc1\n\t"
      "global_load_dwordx4 %13, %16, off offset:784 sc0 sc1\n\t"
      "global_load_dwordx4 %14, %16, off offset:800 sc0 sc1\n\t"
      "global_load_dwordx4 %15, %16, off offset:816 sc0 sc1"
      : "=&v"(b[0]), "=&v"(b[1]), "=&v"(b[2]), "=&v"(b[3]),
        "=&v"(b[4]), "=&v"(b[5]), "=&v"(b[6]), "=&v"(b[7]),
        "=&v"(b[8]), "=&v"(b[9]), "=&v"(b[10]), "=&v"(b[11]),
        "=&v"(b[12]), "=&v"(b[13]), "=&v"(b[14]), "=&v"(b[15])
      : "v"(p) : "memory");
}

__device__ inline bool freshq(const u32x4* b, unsigned tag) {
  unsigned acc = 0;
#pragma unroll
  for (int i = 0; i < 16; ++i) {
    u32x4 v = b[i];
    acc |= (v[0] ^ tag) | (v[1] ^ tag) | (v[2] ^ tag) | (v[3] ^ tag);
  }
  return (acc & 0xFFFF0000u) == 0;
}

// direct data poll: when it breaks, the data is already in b[]
__device__ inline void pollq(const unsigned* p, unsigned tag, u32x4 b[16]) {
  for (;;) {
    load16q(p, b);
    asm volatile("s_waitcnt vmcnt(0)" ::: "memory");
    __builtin_amdgcn_sched_barrier(0);  // rule 18
    if (__ballot(!freshq(b, tag)) == 0) break;
  }
}

// quad jj holds [tag|hi(2jj), tag|lo(2jj), tag|hi(2jj+1), tag|lo(2jj+1)]
__device__ inline void mk8(const u32x4* q, bf16x8& fh, bf16x8& fl) {
  union { unsigned d[4]; bf16x8 v; } H, L;
#pragma unroll
  for (int jj = 0; jj < 4; ++jj) {
    H.d[jj] = (q[jj][0] & 0xFFFFu) | (q[jj][2] << 16);
    L.d[jj] = (q[jj][1] & 0xFFFFu) | (q[jj][3] << 16);
  }
  fh = H.v;
  fl = L.v;
}

__device__ inline void store_pair(unsigned* p, unsigned tag, float v) {
  bf16 hi = (bf16)v;
  bf16 lo = (bf16)(v - (float)hi);
  u32x2 d;
  d[0] = tag | (unsigned)__builtin_bit_cast(unsigned short, hi);
  d[1] = tag | (unsigned)__builtin_bit_cast(unsigned short, lo);
  asm volatile("global_store_dwordx2 %0, %1, off sc0 sc1" ::"v"(p), "v"(d) : "memory");
}

__global__ __launch_bounds__(256, 1)
void mgu_kernel(const float* __restrict__ x,
                const float* __restrict__ Wk, const float* __restrict__ Wr,
                const float* __restrict__ br,
                const float* __restrict__ Wu, const float* __restrict__ Wur,
                const float* __restrict__ bur,
                unsigned* __restrict__ ws0, float* __restrict__ out) {
  __shared__ float red[2][4][2][16][16];  // [phase][wave][ct][row][col16]

  unsigned* Hb = ws0;               // H[2][...]
  unsigned* Gb = ws0 + 2 * HPAR;    // G[2][...]

  const int wg = blockIdx.x;
  const int g = wg & 7, cw = wg >> 3;
  const int c0 = cw * 32;
  const int tid = threadIdx.x;
  const int w = tid >> 6, lane = tid & 63;
  const int dcol = lane & 15, kq = lane >> 4;
  const int rrow = dcol & 7;              // real batch row (dup for MFMA M=16)
  const int kbase = w * 128 + kq * 8;

  // ---- weights into AGPR-pinned registers. Wr/Wur hi+lo; Wk/Wu hi only.
  f32x4 WKH[2][4], WRH[2][4], WRL[2][4], WUH[2][4], WQH[2][4], WQL[2][4];
#pragma unroll
  for (int ct = 0; ct < 2; ++ct) {
    const int col = c0 + ct * 16 + dcol;
#pragma unroll
    for (int kb = 0; kb < 4; ++kb) {
      union { bf16x8 v; f32x4 f; } a_, b_, c_, d_, e_, q_;
#pragma unroll
      for (int j = 0; j < 8; ++j) {
        const size_t ko = (size_t)(kbase + kb * 32 + j) * Uc + col;
        { float v = Wk[ko]; a_.v[j] = (bf16)v; }
        { float v = Wr[ko]; bf16 h0 = (bf16)v; b_.v[j] = h0; c_.v[j] = (bf16)(v - (float)h0); }
        { float v = Wu[ko]; d_.v[j] = (bf16)v; }
        { float v = Wur[ko]; bf16 h0 = (bf16)v; e_.v[j] = h0; q_.v[j] = (bf16)(v - (float)h0); }
      }
      WKH[ct][kb] = a_.f; WRH[ct][kb] = b_.f; WRL[ct][kb] = c_.f;
      WUH[ct][kb] = d_.f; WQH[ct][kb] = e_.f; WQL[ct][kb] = q_.f;
    }
  }
#pragma unroll
  for (int ct = 0; ct < 2; ++ct)
#pragma unroll
    for (int kb = 0; kb < 4; ++kb)
      asm volatile("" : "+a"(WKH[ct][kb]), "+a"(WRH[ct][kb]), "+a"(WRL[ct][kb]),
                       "+a"(WUH[ct][kb]), "+a"(WQH[ct][kb]), "+a"(WQL[ct][kb]));

  // ---- wave-0 finalizer: lane -> (colL, 4 rows 2r+sub); others never finalize
  const int sub = lane >> 5, colL = lane & 31;
  const int fct = colL >> 4, fc16 = colL & 15;
  const float brv = br[c0 + colL], burv = bur[c0 + colL];

  const size_t ldoff = ((size_t)(g * GR + rrow) * Uc + kbase) * 2;
  size_t stoff[4];
#pragma unroll
  for (int r = 0; r < 4; ++r)
    stoff[r] = ((size_t)(g * GR + 2 * r + sub) * Uc + c0 + colL) * 2;

  const float* xptr = x + (size_t)(g * GR + rrow) * Tc * Dc + kbase;

  float h_keep[4] = {0.f, 0.f, 0.f, 0.f}, f_keep[4];
  f32x4 axk[2], axu[2];
  f32x4 xr[8];

  auto do_x_mfma = [&]() {
    bf16x8 xh[4], xl[4];
#pragma unroll
    for (int kb = 0; kb < 4; ++kb) {
      f32x4 a = xr[2 * kb], b = xr[2 * kb + 1];
#pragma unroll
      for (int j = 0; j < 4; ++j) {
        bf16 h0 = (bf16)a[j]; xh[kb][j] = h0; xl[kb][j] = (bf16)(a[j] - (float)h0);
        bf16 h1 = (bf16)b[j]; xh[kb][4 + j] = h1; xl[kb][4 + j] = (bf16)(b[j] - (float)h1);
      }
    }
#pragma unroll
    for (int ct = 0; ct < 2; ++ct) {
      f32x4 k0 = {0.f, 0.f, 0.f, 0.f}, k1 = k0, u0 = k0, u1 = k0;
#pragma unroll
      for (int kb = 0; kb < 4; ++kb) {
        k0 = MFMA16(xh[kb], WB(WKH[ct][kb]), k0);
        k1 = MFMA16(xl[kb], WB(WKH[ct][kb]), k1);
        u0 = MFMA16(xh[kb], WB(WUH[ct][kb]), u0);
        u1 = MFMA16(xl[kb], WB(WUH[ct][kb]), u1);
      }
      axk[ct] = k0 + k1;
      axu[ct] = u0 + u1;
    }
  };

  {  // x(0)
    const float* xp = xptr;
#pragma unroll
    for (int kb = 0; kb < 4; ++kb) {
      xr[2 * kb] = *(const f32x4*)(xp + kb * 32);
      xr[2 * kb + 1] = *(const f32x4*)(xp + kb * 32 + 4);
    }
    do_x_mfma();
  }

  for (int t = 0; t < Tc; ++t) {
    const unsigned tag0 = (unsigned)t << 16, tag1 = (unsigned)(t + 1) << 16;
    const unsigned* Hrd = Hb + (size_t)(t & 1) * HPAR + ldoff;
    const unsigned* Grd = Gb + (size_t)((t + 1) & 1) * HPAR + ldoff;
    unsigned* Gwr = Gb + (size_t)((t + 1) & 1) * HPAR;
    unsigned* Hwr = Hb + (size_t)((t + 1) & 1) * HPAR;
    u32x4 b[16];

    // ---- phase 1: a_f = x@Wk (done) + h@Wr; poll h(t) data directly
    pollq(Hrd, tag0, b);
    if (t + 1 < Tc) {  // x(t+1) prefetch: a full phase of flight before any drain
      const float* xp = xptr + (size_t)(t + 1) * Dc;
#pragma unroll
      for (int kb = 0; kb < 4; ++kb) {
        xr[2 * kb] = *(const f32x4*)(xp + kb * 32);
        xr[2 * kb + 1] = *(const f32x4*)(xp + kb * 32 + 4);
      }
    }
    {
      bf16x8 fh[4], fl[4];
#pragma unroll
      for (int kb = 0; kb < 4; ++kb) mk8(&b[kb * 4], fh[kb], fl[kb]);
#pragma unroll
      for (int ct = 0; ct < 2; ++ct) {
        f32x4 r0 = {0.f, 0.f, 0.f, 0.f}, r1 = r0, r2 = r0;
#pragma unroll
        for (int kb = 0; kb < 4; ++kb) {
          r0 = MFMA16(fh[kb], WB(WRH[ct][kb]), r0);
          r1 = MFMA16(fl[kb], WB(WRH[ct][kb]), r1);
          r2 = MFMA16(fh[kb], WB(WRL[ct][kb]), r2);
        }
        f32x4 r = axk[ct] + r0 + r1 + r2;
#pragma unroll
        for (int i = 0; i < 4; ++i) red[0][w][ct][kq * 4 + i][dcol] = r[i];
      }
    }
    __syncthreads();
    if (w == 0) {  // finalize f for all 8 rows; store g fire-and-forget
#pragma unroll
      for (int r = 0; r < 4; ++r) {
        const int row = 2 * r + sub;
        float af = red[0][0][fct][row][fc16] + red[0][1][fct][row][fc16] +
                   red[0][2][fct][row][fc16] + red[0][3][fct][row][fc16] + brv;
        float f = __builtin_amdgcn_rcpf(1.f + __expf(-af));
        f_keep[r] = f;
        store_pair(Gwr + stoff[r], tag1, h_keep[r] * f);
      }
    }

    // ---- phase 2: a_h = x@Wu (done) + g@Wur; poll g(t+1) data directly
    pollq(Grd, tag1, b);
    {
      bf16x8 gh[4], gl[4];
#pragma unroll
      for (int kb = 0; kb < 4; ++kb) mk8(&b[kb * 4], gh[kb], gl[kb]);
#pragma unroll
      for (int ct = 0; ct < 2; ++ct) {
        f32x4 q0 = {0.f, 0.f, 0.f, 0.f}, q1 = q0, q2 = q0;
#pragma unroll
        for (int kb = 0; kb < 4; ++kb) {
          q0 = MFMA16(gh[kb], WB(WQH[ct][kb]), q0);
          q1 = MFMA16(gl[kb], WB(WQH[ct][kb]), q1);
          q2 = MFMA16(gh[kb], WB(WQL[ct][kb]), q2);
        }
        f32x4 qv = axu[ct] + q0 + q1 + q2;
#pragma unroll
        for (int i = 0; i < 4; ++i) red[1][w][ct][kq * 4 + i][dcol] = qv[i];
      }
    }
    __syncthreads();
    if (w == 0) {  // finalize h(t+1); store fire-and-forget
#pragma unroll
      for (int r = 0; r < 4; ++r) {
        const int row = 2 * r + sub;
        float ah = red[1][0][fct][row][fc16] + red[1][1][fct][row][fc16] +
                   red[1][2][fct][row][fc16] + red[1][3][fct][row][fc16] + burv;
        float e2 = __expf(2.f * ah);
        float hc = 1.f - 2.f * __builtin_amdgcn_rcpf(e2 + 1.f);  // tanh
        float hn = h_keep[r] + f_keep[r] * (hc - h_keep[r]);
        h_keep[r] = hn;
        store_pair(Hwr + stoff[r], tag1, hn);
        if (t == Tc - 1) out[(size_t)(g * GR + row) * Uc + c0 + colL] = hn;
      }
    }
    if (t + 1 < Tc) do_x_mfma();  // x(t+1) convert + x-MFMAs off the wait path
  }
}

extern "C" void kernel_launch(void* const* d_in, const int* in_sizes, int n_in,
                              void* d_out, int out_size, void* d_ws, size_t ws_size,
                              hipStream_t stream) {
  const float* x   = (const float*)d_in[0];
  const float* Wk  = (const float*)d_in[1];
  const float* Wr  = (const float*)d_in[2];
  const float* br  = (const float*)d_in[3];
  const float* Wu  = (const float*)d_in[4];
  const float* Wur = (const float*)d_in[5];
  const float* bur = (const float*)d_in[6];
  float* out = (float*)d_out;

  hipMemsetAsync(d_ws, 0, WS_ZERO, stream);  // h0 = 0 (tag 0), all parities

  hipLaunchKernelGGL(mgu_kernel, dim3(NWG), dim3(256), 0, stream,
                     x, Wk, Wr, br, Wu, Wur, bur, (unsigned*)d_ws, out);
}